// Round 3
// baseline (829.666 us; speedup 1.0000x reference)
//
#include <hip/hip_runtime.h>
#include <cstdint>
#include <cfloat>

// ---------------------------------------------------------------------------
// SimpleVQVAEEncoder, round 3.
// conv_k: scalar-broadcast implicit GEMM, double-buffered LDS (1 barrier/iter),
// register-prefetch staging, wave-uniform k->(ic,ky,kx) on the SALU.
// conv1: 512thr, grid 4608                      (100% occ)
// conv2: 256thr, OC-split 2, grid 1024          (100% occ)
// conv3: 256thr, K-split 4 -> 4 partial buffers (66% occ, deterministic sum in vq)
// ---------------------------------------------------------------------------

constexpr int B_    = 128;
constexpr int HW3   = 169;
constexpr int NPIXT = B_ * HW3;        // 21632
constexpr int NEMB  = 512;
constexpr int EMB   = 64;

// transpose weights [OC][K] -> [K][OC]
__global__ __launch_bounds__(256) void wtrans_kernel(
    const float* __restrict__ w, float* __restrict__ wt, int OC, int K)
{
    int idx = blockIdx.x * 256 + threadIdx.x;
    if (idx >= OC * K) return;
    int oc = idx / K, k = idx - oc * K;
    wt[(size_t)k * OC + oc] = w[idx];
}

template<int IC, int OC, int KH, int KW, int IH, int IW, int OH, int OW,
         int STRIDE, int PAD, bool RELU, bool TRANSOUT, int NTHR, int OCSPL, int KSPL>
__global__ __launch_bounds__(NTHR, 8) void conv_k(
    const float* __restrict__ in, const float* __restrict__ wt,   // wt: [K][OC]
    const float* __restrict__ bias, float* __restrict__ out)
{
    constexpr int K    = IC * KH * KW;
    constexpr int BK   = 32;
    constexpr int NW   = NTHR / 64;
    constexpr int OCQ  = OC / OCSPL;
    constexpr int NOC  = OCQ / NW;
    constexpr int KQ   = K / KSPL;
    constexpr int NITER = KQ / BK;
    constexpr int EPT  = (BK * 64) / NTHR;
    constexpr int HWo  = OH * OW;
    constexpr int ICHW = IC * IH * IW;

    __shared__ float As[2][BK][64];

    const int tid  = threadIdx.x;
    const int lane = tid & 63;
    const int g    = __builtin_amdgcn_readfirstlane(tid >> 6);   // wave id (uniform)

    int bx = blockIdx.x;
    int ks = 0, ocs = 0;
    if (KSPL  > 1) { ks  = bx % KSPL;  bx /= KSPL;  }
    if (OCSPL > 1) { ocs = bx % OCSPL; bx /= OCSPL; }
    const int pg  = bx;
    const int oc0 = ocs * OCQ + g * NOC;
    const int kbase = ks * KQ;

    // per-lane pixel coords (hoisted)
    const int pix  = pg * 64 + lane;
    const int n    = pix / HWo;
    const int hw   = pix - n * HWo;
    const int oy   = hw / OW;
    const int ox   = hw - oy * OW;
    const int row0 = oy * STRIDE - PAD;
    const int col0 = ox * STRIDE - PAD;
    const int prel = row0 * IW + col0;
    const float* inb = in + (size_t)n * ICHW;

    float acc[NOC];
#pragma unroll
    for (int j = 0; j < NOC; j++) acc[j] = 0.f;

    float pv[EPT];
    bool  msk[EPT];

    auto stage_load = [&](int t) {
        const int k0 = kbase + t * BK;
#pragma unroll
        for (int e = 0; e < EPT; e++) {
            int k    = k0 + e * NW + g;          // wave-uniform -> SALU math
            int ic   = k / (KH * KW);
            int r    = k - ic * (KH * KW);
            int ky   = r / KW;
            int kx   = r - ky * KW;
            int koff = ic * (IH * IW) + ky * IW + kx;
            int iy   = row0 + ky;
            int ix   = col0 + kx;
            bool valid = ((unsigned)iy < (unsigned)IH) & ((unsigned)ix < (unsigned)IW);
            int off  = valid ? (prel + koff) : 0;     // safe addr inside image n
            pv[e]  = inb[off];
            msk[e] = valid;
        }
    };
    auto stage_write = [&](int t) {
        float* dst = &As[t & 1][0][0];
#pragma unroll
        for (int e = 0; e < EPT; e++) {
            int kk = e * NW + g;
            dst[kk * 64 + lane] = msk[e] ? pv[e] : 0.f;
        }
    };

    stage_load(0);
    stage_write(0);
    __syncthreads();

    for (int t = 0; t < NITER; t++) {
        if (t + 1 < NITER) stage_load(t + 1);     // loads overlap the FMA burst
        const float* bp = wt + (size_t)(kbase + t * BK) * OC + oc0;
        const float* ap = &As[t & 1][0][0];
#pragma unroll
        for (int kk = 0; kk < BK; kk++) {
            float av = ap[kk * 64 + lane];
#pragma unroll
            for (int j = 0; j < NOC; j++)
                acc[j] = fmaf(av, bp[kk * OC + j], acc[j]);  // SGPR weight operand
        }
        if (t + 1 < NITER) stage_write(t + 1);
        __syncthreads();
    }

    // epilogue
    if (KSPL > 1) {
        float* outp = out + (size_t)ks * OC * NPIXT;          // raw partial, [oc][pix]
#pragma unroll
        for (int j = 0; j < NOC; j++)
            outp[(size_t)(oc0 + j) * NPIXT + pix] = acc[j];
    } else {
#pragma unroll
        for (int j = 0; j < NOC; j++) {
            int oc = oc0 + j;
            float v = acc[j] + bias[oc];
            if (RELU) v = fmaxf(v, 0.f);
            if (TRANSOUT) out[(size_t)oc * NPIXT + pix] = v;
            else          out[((size_t)(n * OC + oc)) * HWo + hw] = v;
        }
    }
}

// ---------------------------------------------------------------------------
// VQ: per pixel argmin over 512 codes. z = sum of 4 conv3 K-partials + b3
// (fixed summation order -> deterministic). Codebook reads wave-uniform.
// ---------------------------------------------------------------------------
__global__ __launch_bounds__(256) void vq_kernel(
    const float* __restrict__ zp,           // [4][64][21632] partials
    const float* __restrict__ b3,           // [64]
    const float* __restrict__ cb,           // [512][64]
    unsigned long long* __restrict__ best)  // [21632], preset to ~0
{
    const int tid  = threadIdx.x;
    const int lane = tid & 63;
    const int wv   = tid >> 6;
    const int pg   = blockIdx.x >> 1;
    const int half = blockIdx.x & 1;
    const int p    = pg * 64 + lane;        // 338*64 == 21632 exactly

    __shared__ float c2s[256];
    {
        int code = half * 256 + tid;
        const float* c = cb + (size_t)code * EMB;
        float s = 0.f;
#pragma unroll
        for (int j = 0; j < EMB; j += 4) {
            float4 v = *(const float4*)(c + j);
            s = fmaf(v.x, v.x, s); s = fmaf(v.y, v.y, s);
            s = fmaf(v.z, v.z, s); s = fmaf(v.w, v.w, s);
        }
        c2s[tid] = s;
    }
    __syncthreads();

    constexpr size_t PSTR = (size_t)EMB * NPIXT;
    float zr[EMB];
    float zz = 0.f;
#pragma unroll
    for (int j = 0; j < EMB; j++) {
        size_t o = (size_t)j * NPIXT + p;
        float v = (zp[o] + zp[PSTR + o]) + (zp[2 * PSTR + o] + zp[3 * PSTR + o]);
        v += b3[j];
        zr[j] = v;
        zz = fmaf(v, v, zz);
    }

    float bestScore = FLT_MAX;
    int   bestIdx   = 0x7fffffff;
    const int base = half * 256 + wv * 64;
    for (int ci = 0; ci < 64; ci++) {
        int code = __builtin_amdgcn_readfirstlane(base + ci);
        const float* c = cb + (size_t)code * EMB;
        float dot = 0.f;
#pragma unroll
        for (int j = 0; j < EMB; j++) dot = fmaf(zr[j], c[j], dot);
        float score = fmaf(-2.f, dot, zz) + c2s[code - half * 256];
        if (score < bestScore) { bestScore = score; bestIdx = code; }
    }

    unsigned u = __float_as_uint(bestScore);
    u = (bestScore < 0.f) ? ~u : (u | 0x80000000u);
    unsigned long long pk = ((unsigned long long)u << 32) | (unsigned)bestIdx;
    atomicMin(&best[p], pk);
}

__global__ __launch_bounds__(256) void onehot_kernel(
    const unsigned long long* __restrict__ best, float* __restrict__ out)
{
    int p = blockIdx.x * 256 + threadIdx.x;
    if (p >= NPIXT) return;
    int code = (int)(unsigned)(best[p] & 0xffffffffu);
    int b  = p / HW3;
    int hw = p - b * HW3;
    out[((size_t)b * NEMB + code) * HW3 + hw] = 1.0f;
}

extern "C" void kernel_launch(void* const* d_in, const int* in_sizes, int n_in,
                              void* d_out, int out_size, void* d_ws, size_t ws_size,
                              hipStream_t stream) {
    const float* x  = (const float*)d_in[0];
    const float* w1 = (const float*)d_in[1];
    const float* b1 = (const float*)d_in[2];
    const float* w2 = (const float*)d_in[3];
    const float* b2 = (const float*)d_in[4];
    const float* w3 = (const float*)d_in[5];
    const float* b3 = (const float*)d_in[6];
    const float* cb = (const float*)d_in[7];
    float* out = (float*)d_out;

    // workspace layout (z3 partials alias z1's region — z1 dead after conv2):
    float* z1  = (float*)d_ws;                            // 75.5 MB
    float* z3p = z1;                                      // 4 x 5.5 MB = 22.1 MB
    float* z2  = z1 + (size_t)128 * 64 * 48 * 48;         // 16.8 MB
    unsigned long long* best = (unsigned long long*)(z2 + (size_t)128 * 128 * 16 * 16);
    float* w1t = (float*)(best + NPIXT);                  // [192][64]
    float* w2t = w1t + 192 * 64;                          // [2304][128]
    float* w3t = w2t + 2304 * 128;                        // [2048][64]

    hipMemsetAsync(out, 0, (size_t)out_size * sizeof(float), stream);
    hipMemsetAsync(best, 0xFF, (size_t)NPIXT * sizeof(unsigned long long), stream);

    wtrans_kernel<<<(64 * 192 + 255) / 256, 256, 0, stream>>>(w1, w1t, 64, 192);
    wtrans_kernel<<<(128 * 2304 + 255) / 256, 256, 0, stream>>>(w2, w2t, 128, 2304);
    wtrans_kernel<<<(64 * 2048 + 255) / 256, 256, 0, stream>>>(w3, w3t, 64, 2048);

    // conv1: M=294912 -> 4608 blocks x 512thr
    conv_k<3, 64, 8, 8, 192, 192, 48, 48, 4, 2, true, false, 512, 1, 1>
        <<<4608, 512, 0, stream>>>(x, w1t, b1, z1);
    // conv2: M=32768, OC-split 2 -> 1024 blocks x 256thr
    conv_k<64, 128, 6, 6, 48, 48, 16, 16, 3, 2, true, false, 256, 2, 1>
        <<<1024, 256, 0, stream>>>(z1, w2t, b2, z2);
    // conv3: M=21632, K-split 4 -> 1352 blocks x 256thr, raw partials [oc][pix]
    conv_k<128, 64, 4, 4, 16, 16, 13, 13, 1, 0, false, true, 256, 1, 4>
        <<<1352, 256, 0, stream>>>(z2, w3t, nullptr, z3p);

    vq_kernel<<<338 * 2, 256, 0, stream>>>(z3p, b3, cb, best);
    onehot_kernel<<<(NPIXT + 255) / 256, 256, 0, stream>>>(best, out);
}